// Round 4
// baseline (286.859 us; speedup 1.0000x reference)
//
#include <hip/hip_runtime.h>
#include <hip/hip_bf16.h>
#include <math.h>

// MultiSimilarityLoss on MI355X.
// x: [n,128] fp32 L2-normalized; t: [n] int32 labels; out: 4 fp32
// (loss, prec, mean_pos_sim(last row), mean_neg_sim(last row)).
// ep = EPOCH_NUM/300 = 1.0, BASE=0.5, POS_MARGIN=0.9, NEG_MARGIN=0.1.
//
// R4: epilogue diet (fast exp, ballot instead of count-reduce, global
// atomics direct) + label-group LDS pos kernel (rows staged once).
// exp args expanded: neg 50(s-.5)+(.1-s)^2 = s^2+49.8s-24.99
//                    pos -2(s-.5)+(s-.9)^2 = s^2-3.8s+1.81

#define D 128
#define NL 128   // labels are 0..99; padded

typedef __attribute__((ext_vector_type(8))) short short8;
typedef __attribute__((ext_vector_type(4))) float float4v;

// ---------------- wave/block reduce helpers ----------------
__device__ inline float waveSum(float v) {
    #pragma unroll
    for (int o = 32; o > 0; o >>= 1) v += __shfl_down(v, o, 64);
    return v;
}
__device__ inline float waveMin(float v) {
    #pragma unroll
    for (int o = 32; o > 0; o >>= 1) v = fminf(v, __shfl_down(v, o, 64));
    return v;
}

// ---------------- kernel A: fp32->bf16 convert + label bucketing ------------
// blocks [0, nconv): convert 8 floats/thread. block nconv: bucket by label.
__global__ __launch_bounds__(256) void prep_kernel(
    const float* __restrict__ x, ushort* __restrict__ xb, int total8,
    const int* __restrict__ t, int* __restrict__ offs, int* __restrict__ list,
    int n, int nconv)
{
    const int tid = threadIdx.x;
    if ((int)blockIdx.x < nconv) {
        const int g = blockIdx.x * 256 + tid;
        if (g >= total8) return;
        const float4* src = (const float4*)(x) + g * 2;
        float4 a = src[0], b = src[1];
        float f[8] = {a.x, a.y, a.z, a.w, b.x, b.y, b.z, b.w};
        ushort r[8];
        #pragma unroll
        for (int i = 0; i < 8; ++i) {
            unsigned u = __float_as_uint(f[i]);
            r[i] = (ushort)((u + 0x7FFFu + ((u >> 16) & 1u)) >> 16);   // RNE
        }
        uint4 packed;
        packed.x = (unsigned)r[0] | ((unsigned)r[1] << 16);
        packed.y = (unsigned)r[2] | ((unsigned)r[3] << 16);
        packed.z = (unsigned)r[4] | ((unsigned)r[5] << 16);
        packed.w = (unsigned)r[6] | ((unsigned)r[7] << 16);
        ((uint4*)xb)[g] = packed;
        return;
    }
    // bucketing block
    __shared__ int cnt[NL], cur[NL];
    if (tid < NL) cnt[tid] = 0;
    __syncthreads();
    for (int j = tid; j < n; j += 256) atomicAdd(&cnt[t[j]], 1);
    __syncthreads();
    if (tid == 0) {
        int acc = 0;
        for (int g = 0; g < NL; ++g) { cur[g] = acc; offs[g] = acc; acc += cnt[g]; }
        offs[NL] = acc;
    }
    __syncthreads();
    for (int j = tid; j < n; j += 256) {
        int p = atomicAdd(&cur[t[j]], 1);
        list[p] = j;
    }
}

// ---------------- kernel B: per-row positive stats, label-group LDS --------
// One block per label group. Group cols (bf16) staged in LDS once (chunked if
// >128); 8 waves each own one row per iteration (own row fp32 in LDS).
#define CC 128   // col chunk

__global__ __launch_bounds__(512) void pos_kernel3(
    const float* __restrict__ x, const ushort* __restrict__ xb,
    const int* __restrict__ offs, const int* __restrict__ list,
    float* __restrict__ pos_min, float* __restrict__ pos_sum,
    float* __restrict__ last4, int n)
{
    const int g = blockIdx.x;
    const int s0 = offs[g], m = offs[g + 1] - s0;
    if (m <= 0) return;

    __shared__ __align__(16) uint4 cb[CC * 16];     // 32 KB col chunk (swizzled)
    __shared__ __align__(16) float xi[8][D];        // 4 KB own rows

    const int tid = threadIdx.x;
    const int wid = tid >> 6, lane = tid & 63;
    const bool multi = (m > CC);

    if (!multi) {   // stage all cols once
        for (int idx = tid; idx < m * 16; idx += 512) {
            int cl = idx >> 4, q = idx & 15;
            cb[cl * 16 + (q ^ (cl & 15))] = ((const uint4*)xb)[(size_t)list[s0 + cl] * 16 + q];
        }
        __syncthreads();
    }

    for (int r0 = 0; r0 < m; r0 += 8) {
        const int r = r0 + wid;
        const int i = (r < m) ? list[s0 + r] : 0;
        if (r < m && lane < 32)   // own row fp32 -> LDS (intra-wave only)
            ((float4*)xi[wid])[lane] = ((const float4*)(x + (size_t)i * D))[lane];

        float mn = INFINITY, ps = 0.f, ss = 0.f, sc = 0.f;
        for (int c0 = 0; c0 < m; c0 += CC) {
            const int cc = min(CC, m - c0);
            if (multi) {
                __syncthreads();
                for (int idx = tid; idx < cc * 16; idx += 512) {
                    int cl = idx >> 4, q = idx & 15;
                    cb[cl * 16 + (q ^ (cl & 15))] = ((const uint4*)xb)[(size_t)list[s0 + c0 + cl] * 16 + q];
                }
                __syncthreads();
            }
            if (r < m) {
                const float* xu = xi[wid];
                for (int cl = lane; cl < cc; cl += 64) {
                    float d = 0.f;
                    #pragma unroll
                    for (int q = 0; q < 16; ++q) {
                        uint4 v = cb[cl * 16 + (q ^ (cl & 15))];
                        const float* u = xu + q * 8;
                        d += __uint_as_float(v.x << 16)         * u[0];
                        d += __uint_as_float(v.x & 0xffff0000u) * u[1];
                        d += __uint_as_float(v.y << 16)         * u[2];
                        d += __uint_as_float(v.y & 0xffff0000u) * u[3];
                        d += __uint_as_float(v.z << 16)         * u[4];
                        d += __uint_as_float(v.z & 0xffff0000u) * u[5];
                        d += __uint_as_float(v.w << 16)         * u[6];
                        d += __uint_as_float(v.w & 0xffff0000u) * u[7];
                    }
                    if (d < 0.9f) {            // excludes j==i (sim ~ 1.0)
                        mn = fminf(mn, d);
                        ps += __expf(fmaf(d, d, fmaf(-3.8f, d, 1.81f)));
                        ss += d; sc += 1.f;
                    }
                }
            }
        }
        mn = waveMin(mn); ps = waveSum(ps); ss = waveSum(ss); sc = waveSum(sc);
        if (r < m && lane == 0) {
            pos_min[i] = mn;
            pos_sum[i] = ps;
            if (i == n - 1) { last4[0] = ss; last4[1] = sc; }
        }
    }
}

// ---------------- kernel C: MFMA sim GEMM + negative epilogue ---------------
// 128x128 tile per 256-thread block (4 waves, each 64x64 via 4x4 MFMA tiles).
__global__ __launch_bounds__(256) void neg_kernel_mfma(
    const ushort* __restrict__ xb, const int* __restrict__ t,
    const float* __restrict__ pos_min,
    float* __restrict__ neg_sum, float* __restrict__ neg_cnt,
    float* __restrict__ last4, int n)
{
    __shared__ __align__(16) ushort A_lds[128 * 128];   // 32 KB
    __shared__ __align__(16) ushort B_lds[128 * 128];   // 32 KB
    __shared__ int   labr[128], labc[128];
    __shared__ float pmins[128];

    const int tid = threadIdx.x;
    const int w = tid >> 6, lane = tid & 63;
    const int wy = w >> 1, wx = w & 1;
    const int quad = lane >> 4, lq = lane & 15;
    const int i0 = blockIdx.y * 128, j0 = blockIdx.x * 128;

    for (int l = tid; l < 128; l += 256) {
        labr[l] = t[i0 + l];
        labc[l] = t[j0 + l];
        pmins[l] = pos_min[i0 + l];
    }

    // stage A,B tiles (bf16, 16B chunks, swizzled: chunk c -> c ^ (row&15))
    {
        const uint4* xbv = (const uint4*)xb;
        uint4* Au = (uint4*)A_lds;
        uint4* Bu = (uint4*)B_lds;
        #pragma unroll
        for (int it = 0; it < 8; ++it) {
            int gidx = tid + it * 256;
            int row = gidx >> 4, c = gidx & 15;
            int cs = c ^ (row & 15);
            Au[row * 16 + cs] = xbv[(size_t)(i0 + row) * 16 + c];
            Bu[row * 16 + cs] = xbv[(size_t)(j0 + row) * 16 + c];
        }
    }
    __syncthreads();

    float4v acc[4][4];
    #pragma unroll
    for (int r = 0; r < 4; ++r)
        #pragma unroll
        for (int c = 0; c < 4; ++c) acc[r][c] = (float4v){0.f, 0.f, 0.f, 0.f};

    const short8* As = (const short8*)A_lds;
    const short8* Bs = (const short8*)B_lds;
    #pragma unroll
    for (int s = 0; s < 4; ++s) {            // K-step: k = s*32 + quad*8 + j
        const int swz = (s * 4 + quad) ^ lq;
        short8 a[4], b[4];
        #pragma unroll
        for (int tt = 0; tt < 4; ++tt) {
            a[tt] = As[(wy * 64 + tt * 16 + lq) * 16 + swz];
            b[tt] = Bs[(wx * 64 + tt * 16 + lq) * 16 + swz];
        }
        #pragma unroll
        for (int tr = 0; tr < 4; ++tr)
            #pragma unroll
            for (int tc = 0; tc < 4; ++tc)
                acc[tr][tc] = __builtin_amdgcn_mfma_f32_16x16x32_bf16(
                    a[tr], b[tc], acc[tr][tc], 0, 0, 0);
    }

    // epilogue: C/D layout col=lane&15, row=quad*4+reg (per 16x16 tile)
    int lc[4];
    #pragma unroll
    for (int tc = 0; tc < 4; ++tc) lc[tc] = labc[wx * 64 + tc * 16 + lq];

    #pragma unroll
    for (int tr = 0; tr < 4; ++tr) {
        #pragma unroll
        for (int reg = 0; reg < 4; ++reg) {
            const int row_loc = wy * 64 + tr * 16 + quad * 4 + reg;
            const int gi = i0 + row_loc;
            const float pthr = pmins[row_loc] - 0.5f;
            const int lr = labr[row_loc];
            float ns = 0.f;
            bool any = false;
            #pragma unroll
            for (int tc = 0; tc < 4; ++tc) {
                const float s = acc[tr][tc][reg];
                if ((lr != lc[tc]) & (s > 0.1f) & (s > pthr)) {
                    ns += __expf(fmaf(s, s, fmaf(49.8f, s, -24.99f)));
                    any = true;
                }
            }
            #pragma unroll
            for (int o = 1; o < 16; o <<= 1) ns += __shfl_xor(ns, o, 64);
            unsigned long long b = __ballot(any);
            const bool rowhas = ((b >> (quad * 16)) & 0xFFFFull) != 0ull;
            if (lq == 0 && rowhas) {
                atomicAdd(&neg_sum[gi], ns);
                atomicAdd(&neg_cnt[gi], 1.0f);
            }
            if (gi == n - 1) {   // exact stats for the global last row
                float ssim = 0.f, ncf = 0.f;
                #pragma unroll
                for (int tc = 0; tc < 4; ++tc) {
                    const float s = acc[tr][tc][reg];
                    if ((lr != lc[tc]) & (s > 0.1f) & (s > pthr)) { ssim += s; ncf += 1.f; }
                }
                #pragma unroll
                for (int o = 1; o < 16; o <<= 1) {
                    ssim += __shfl_xor(ssim, o, 64);
                    ncf  += __shfl_xor(ncf, o, 64);
                }
                if (lq == 0 && ncf > 0.f) {
                    atomicAdd(&last4[2], ssim);
                    atomicAdd(&last4[3], ncf);
                }
            }
        }
    }
}

// ---------------- kernel D: finalize ----------------
__global__ __launch_bounds__(256) void finalize_kernel(
    const float* __restrict__ pos_sum, const float* __restrict__ neg_sum,
    const float* __restrict__ neg_cnt, const float* __restrict__ last4,
    float* __restrict__ out, int n)
{
    const int tid = threadIdx.x;
    __shared__ float rbuf[2][4];
    float lsum = 0.f, nno = 0.f;
    for (int i = tid; i < n; i += 256) {
        float nc = neg_cnt[i];
        if (nc > 0.f)
            lsum += 0.5f * log1pf(pos_sum[i]) + (1.0f / 50.0f) * log1pf(neg_sum[i]);
        else
            nno += 1.f;
    }
    const int lane = tid & 63, wid = tid >> 6;
    lsum = waveSum(lsum); nno = waveSum(nno);
    if (lane == 0) { rbuf[0][wid] = lsum; rbuf[1][wid] = nno; }
    __syncthreads();
    if (tid == 0) {
        float L = rbuf[0][0] + rbuf[0][1] + rbuf[0][2] + rbuf[0][3];
        float P = rbuf[1][0] + rbuf[1][1] + rbuf[1][2] + rbuf[1][3];
        out[0] = L / (float)n;
        out[1] = P / (float)n;
        out[2] = last4[0] / fmaxf(last4[1], 1.f);
        out[3] = last4[2] / fmaxf(last4[3], 1.f);
    }
}

// ---------------- launch ----------------
extern "C" void kernel_launch(void* const* d_in, const int* in_sizes, int n_in,
                              void* d_out, int out_size, void* d_ws, size_t ws_size,
                              hipStream_t stream) {
    const float* x = (const float*)d_in[0];
    const int*   t = (const int*)d_in[1];
    const int n = in_sizes[1];   // 8192

    float* ws      = (float*)d_ws;
    float* pos_min = ws;                      // [n]
    float* pos_sum = ws + n;                  // [n]
    float* neg_sum = ws + 2 * n;              // [n] zero-init
    float* neg_cnt = ws + 3 * n;              // [n] zero-init
    float* last4   = ws + 4 * n;              // [4]  zero-init
    int*   offs    = (int*)(ws + 4 * n + 4);          // [NL+1]
    int*   list    = (int*)(ws + 4 * n + 4 + NL + 1); // [n]
    size_t xb_off = (size_t)(5 * n + 133 + 3) & ~(size_t)3;
    ushort* xb = (ushort*)(ws + xb_off);              // [n*128] bf16, 16B aligned

    hipMemsetAsync(neg_sum, 0, (size_t)(2 * n + 4) * sizeof(float), stream);

    const int total8 = n * D / 8;
    const int nconv = (total8 + 255) / 256;
    prep_kernel<<<nconv + 1, 256, 0, stream>>>(x, xb, total8, t, offs, list, n, nconv);

    pos_kernel3<<<NL, 512, 0, stream>>>(x, xb, offs, list,
                                        pos_min, pos_sum, last4, n);

    dim3 grid(n / 128, n / 128);
    neg_kernel_mfma<<<grid, 256, 0, stream>>>(xb, t, pos_min,
                                              neg_sum, neg_cnt, last4, n);

    finalize_kernel<<<1, 256, 0, stream>>>(pos_sum, neg_sum, neg_cnt, last4,
                                           (float*)d_out, n);
}

// Round 5
// 143.094 us; speedup vs baseline: 2.0047x; 2.0047x over previous
//
#include <hip/hip_runtime.h>
#include <hip/hip_bf16.h>
#include <math.h>

// MultiSimilarityLoss on MI355X.
// x: [n,128] fp32 L2-normalized; t: [n] int32 labels; out: 4 fp32
// (loss, prec, mean_pos_sim(last row), mean_neg_sim(last row)).
// ep = EPOCH_NUM/300 = 1.0, BASE=0.5, POS_MARGIN=0.9, NEG_MARGIN=0.1.
//
// R5: (a) triangular tiles (sim symmetric): 2080 blocks instead of 4096,
// off-diag tiles accumulate row-sums AND transposed col-sums from one acc;
// (b) no global atomic contention: LDS transpose reduce (aliased onto A_lds)
// -> 8-slice partial buffer, <=8 writers/address; neg_cnt eliminated
// (has_neg <=> sum of exp > 0, every term >= e^-20 > 0 in fp32);
// (c) pos kernel split 8 sub-blocks per label group for occupancy.
// exp args expanded: neg 50(s-.5)+(.1-s)^2 = s^2+49.8s-24.99
//                    pos -2(s-.5)+(s-.9)^2 = s^2-3.8s+1.81

#define D 128
#define NL 128   // labels are 0..99; padded

typedef __attribute__((ext_vector_type(8))) short short8;
typedef __attribute__((ext_vector_type(4))) float float4v;

// ---------------- wave reduce helpers ----------------
__device__ inline float waveSum(float v) {
    #pragma unroll
    for (int o = 32; o > 0; o >>= 1) v += __shfl_down(v, o, 64);
    return v;
}
__device__ inline float waveMin(float v) {
    #pragma unroll
    for (int o = 32; o > 0; o >>= 1) v = fminf(v, __shfl_down(v, o, 64));
    return v;
}

// ---------------- kernel A: fp32->bf16 convert + label bucketing ------------
__global__ __launch_bounds__(256) void prep_kernel(
    const float* __restrict__ x, ushort* __restrict__ xb, int total8,
    const int* __restrict__ t, int* __restrict__ offs, int* __restrict__ list,
    int n, int nconv)
{
    const int tid = threadIdx.x;
    if ((int)blockIdx.x < nconv) {
        const int g = blockIdx.x * 256 + tid;
        if (g >= total8) return;
        const float4* src = (const float4*)(x) + g * 2;
        float4 a = src[0], b = src[1];
        float f[8] = {a.x, a.y, a.z, a.w, b.x, b.y, b.z, b.w};
        ushort r[8];
        #pragma unroll
        for (int i = 0; i < 8; ++i) {
            unsigned u = __float_as_uint(f[i]);
            r[i] = (ushort)((u + 0x7FFFu + ((u >> 16) & 1u)) >> 16);   // RNE
        }
        uint4 packed;
        packed.x = (unsigned)r[0] | ((unsigned)r[1] << 16);
        packed.y = (unsigned)r[2] | ((unsigned)r[3] << 16);
        packed.z = (unsigned)r[4] | ((unsigned)r[5] << 16);
        packed.w = (unsigned)r[6] | ((unsigned)r[7] << 16);
        ((uint4*)xb)[g] = packed;
        return;
    }
    // bucketing block
    __shared__ int cnt[NL], cur[NL];
    if (tid < NL) cnt[tid] = 0;
    __syncthreads();
    for (int j = tid; j < n; j += 256) atomicAdd(&cnt[t[j]], 1);
    __syncthreads();
    if (tid == 0) {
        int acc = 0;
        for (int g = 0; g < NL; ++g) { cur[g] = acc; offs[g] = acc; acc += cnt[g]; }
        offs[NL] = acc;
    }
    __syncthreads();
    for (int j = tid; j < n; j += 256) {
        int p = atomicAdd(&cur[t[j]], 1);
        list[p] = j;
    }
}

// ---------------- kernel B: per-row positive stats, label-group LDS --------
// grid (NL, 8): each label group split over 8 sub-blocks of 256 threads.
__global__ __launch_bounds__(256) void pos_kernel3(
    const float* __restrict__ x, const ushort* __restrict__ xb,
    const int* __restrict__ offs, const int* __restrict__ list,
    float* __restrict__ pos_min, float* __restrict__ pos_sum,
    float* __restrict__ last4, int n)
{
    const int g = blockIdx.x, sub = blockIdx.y;
    const int s0 = offs[g], m = offs[g + 1] - s0;
    if (m <= 0) return;
    const int chunk = (m + 7) >> 3;
    const int rb = sub * chunk, re = min(m, rb + chunk);
    if (rb >= re) return;    // uniform per block, before any barrier

    __shared__ __align__(16) uint4 cb[128 * 16];    // 32 KB col chunk (swizzled)
    __shared__ __align__(16) float xi[4][D];        // own rows (fp32)

    const int tid = threadIdx.x;
    const int wid = tid >> 6, lane = tid & 63;
    const bool multi = (m > 128);

    if (!multi) {   // stage all group cols once
        for (int idx = tid; idx < m * 16; idx += 256) {
            int cl = idx >> 4, q = idx & 15;
            cb[cl * 16 + (q ^ (cl & 15))] =
                ((const uint4*)xb)[(size_t)list[s0 + cl] * 16 + q];
        }
        __syncthreads();
    }

    for (int r0 = rb; r0 < re; r0 += 4) {
        const int r = r0 + wid;
        const bool active = (r < re);
        const int i = active ? list[s0 + r] : 0;
        if (active && lane < 32)
            ((float4*)xi[wid])[lane] = ((const float4*)(x + (size_t)i * D))[lane];

        float mn = INFINITY, ps = 0.f, ss = 0.f, sc = 0.f;
        for (int c0 = 0; c0 < m; c0 += 128) {
            const int cc = min(128, m - c0);
            if (multi) {
                __syncthreads();
                for (int idx = tid; idx < cc * 16; idx += 256) {
                    int cl = idx >> 4, q = idx & 15;
                    cb[cl * 16 + (q ^ (cl & 15))] =
                        ((const uint4*)xb)[(size_t)list[s0 + c0 + cl] * 16 + q];
                }
                __syncthreads();
            }
            if (active) {
                const float* xu = xi[wid];
                for (int cl = lane; cl < cc; cl += 64) {
                    float d = 0.f;
                    #pragma unroll
                    for (int q = 0; q < 16; ++q) {
                        uint4 v = cb[cl * 16 + (q ^ (cl & 15))];
                        const float* u = xu + q * 8;
                        d += __uint_as_float(v.x << 16)         * u[0];
                        d += __uint_as_float(v.x & 0xffff0000u) * u[1];
                        d += __uint_as_float(v.y << 16)         * u[2];
                        d += __uint_as_float(v.y & 0xffff0000u) * u[3];
                        d += __uint_as_float(v.z << 16)         * u[4];
                        d += __uint_as_float(v.z & 0xffff0000u) * u[5];
                        d += __uint_as_float(v.w << 16)         * u[6];
                        d += __uint_as_float(v.w & 0xffff0000u) * u[7];
                    }
                    if (d < 0.9f) {            // excludes j==i (sim ~ 1.0)
                        mn = fminf(mn, d);
                        ps += __expf(fmaf(d, d, fmaf(-3.8f, d, 1.81f)));
                        ss += d; sc += 1.f;
                    }
                }
            }
        }
        mn = waveMin(mn); ps = waveSum(ps); ss = waveSum(ss); sc = waveSum(sc);
        if (active && lane == 0) {
            pos_min[i] = mn;
            pos_sum[i] = ps;
            if (i == n - 1) { last4[0] = ss; last4[1] = sc; }
        }
    }
}

// ---------------- kernel C: triangular MFMA sim + negative epilogue --------
// 1D grid over lower-triangular 128x128 tiles (r >= c). Off-diag tiles add
// both row-sums (rows i0=r*128) and transposed col-sums (rows j0=c*128).
__global__ __launch_bounds__(256) void neg_kernel_tri(
    const ushort* __restrict__ xb, const int* __restrict__ t,
    const float* __restrict__ pos_min,
    float* __restrict__ part, float* __restrict__ last4, int n)
{
    __shared__ __align__(16) ushort A_lds[128 * 128];   // 32 KB
    __shared__ __align__(16) ushort B_lds[128 * 128];   // 32 KB
    __shared__ int   labr[128], labc[128];
    __shared__ float pmins[128], pminc[128];

    // triangular decode: block b -> (r, c), r >= c
    int b = blockIdx.x;
    int r = (int)((sqrtf(8.0f * (float)b + 1.0f) - 1.0f) * 0.5f);
    while ((r + 1) * (r + 2) / 2 <= b) ++r;
    while (r * (r + 1) / 2 > b) --r;
    const int c = b - r * (r + 1) / 2;
    const bool offdiag = (r != c);

    const int tid = threadIdx.x;
    const int w = tid >> 6, lane = tid & 63;
    const int wy = w >> 1, wx = w & 1;
    const int quad = lane >> 4, lq = lane & 15;
    const int i0 = r * 128, j0 = c * 128;

    for (int l = tid; l < 128; l += 256) {
        labr[l] = t[i0 + l];
        labc[l] = t[j0 + l];
        pmins[l] = pos_min[i0 + l];
        pminc[l] = pos_min[j0 + l];
    }

    // stage A,B tiles (bf16, 16B chunks, swizzled: chunk q -> q ^ (row&15))
    {
        const uint4* xbv = (const uint4*)xb;
        uint4* Au = (uint4*)A_lds;
        uint4* Bu = (uint4*)B_lds;
        #pragma unroll
        for (int it = 0; it < 8; ++it) {
            int gidx = tid + it * 256;
            int row = gidx >> 4, q = gidx & 15;
            int qs = q ^ (row & 15);
            Au[row * 16 + qs] = xbv[(size_t)(i0 + row) * 16 + q];
            Bu[row * 16 + qs] = xbv[(size_t)(j0 + row) * 16 + q];
        }
    }
    __syncthreads();

    float4v acc[4][4];
    #pragma unroll
    for (int a = 0; a < 4; ++a)
        #pragma unroll
        for (int d2 = 0; d2 < 4; ++d2) acc[a][d2] = (float4v){0.f, 0.f, 0.f, 0.f};

    {
        const short8* As = (const short8*)A_lds;
        const short8* Bs = (const short8*)B_lds;
        #pragma unroll
        for (int s = 0; s < 4; ++s) {            // K-step: k = s*32 + quad*8 + j
            const int swz = (s * 4 + quad) ^ lq;
            short8 af[4], bf[4];
            #pragma unroll
            for (int tt = 0; tt < 4; ++tt) {
                af[tt] = As[(wy * 64 + tt * 16 + lq) * 16 + swz];
                bf[tt] = Bs[(wx * 64 + tt * 16 + lq) * 16 + swz];
            }
            #pragma unroll
            for (int tr = 0; tr < 4; ++tr)
                #pragma unroll
                for (int tc = 0; tc < 4; ++tc)
                    acc[tr][tc] = __builtin_amdgcn_mfma_f32_16x16x32_bf16(
                        af[tr], bf[tc], acc[tr][tc], 0, 0, 0);
        }
    }
    __syncthreads();     // all waves done reading A/B before aliasing

    float* pp_r = (float*)A_lds;   // [32][129] row partials
    float* pp_c = (float*)B_lds;   // [8][129]  col partials

    int lcv[4]; float pthc[4];
    #pragma unroll
    for (int tc = 0; tc < 4; ++tc) {
        const int cl = wx * 64 + tc * 16 + lq;
        lcv[tc] = labc[cl];
        pthc[tc] = pminc[cl] - 0.5f;
    }
    float colp[4] = {0.f, 0.f, 0.f, 0.f};

    #pragma unroll
    for (int tr = 0; tr < 4; ++tr) {
        #pragma unroll
        for (int reg = 0; reg < 4; ++reg) {
            const int row_loc = wy * 64 + tr * 16 + quad * 4 + reg;
            const float pthr = pmins[row_loc] - 0.5f;
            const int lr = labr[row_loc];
            float ns = 0.f;
            #pragma unroll
            for (int tc = 0; tc < 4; ++tc) {
                const float s = acc[tr][tc][reg];
                const bool base = (lr != lcv[tc]) & (s > 0.1f);
                const float e = __expf(fmaf(s, s, fmaf(49.8f, s, -24.99f)));
                ns      += (base & (s > pthr))     ? e : 0.f;
                colp[tc] += (base & (s > pthc[tc])) ? e : 0.f;
            }
            pp_r[(wx * 16 + lq) * 129 + row_loc] = ns;

            const int gi = i0 + row_loc;
            if (gi == n - 1) {   // exact stats for the global last row
                float ssim = 0.f, ncf = 0.f;
                #pragma unroll
                for (int tc = 0; tc < 4; ++tc) {
                    const float s = acc[tr][tc][reg];
                    if ((lr != lcv[tc]) & (s > 0.1f) & (s > pthr)) { ssim += s; ncf += 1.f; }
                }
                #pragma unroll
                for (int o = 1; o < 16; o <<= 1) {
                    ssim += __shfl_xor(ssim, o, 64);
                    ncf  += __shfl_xor(ncf, o, 64);
                }
                if (lq == 0 && ncf > 0.f) {
                    atomicAdd(&last4[2], ssim);
                    atomicAdd(&last4[3], ncf);
                }
            }
        }
    }
    #pragma unroll
    for (int tc = 0; tc < 4; ++tc)
        pp_c[(wy * 4 + quad) * 129 + (wx * 64 + tc * 16 + lq)] = colp[tc];
    __syncthreads();

    if (tid < 128) {
        float s = 0.f;
        #pragma unroll
        for (int cc = 0; cc < 32; ++cc) s += pp_r[cc * 129 + tid];
        atomicAdd(&part[(size_t)(c & 7) * n + i0 + tid], s);   // <=8 writers/slice
        if (offdiag) {
            float s2 = 0.f;
            #pragma unroll
            for (int cc = 0; cc < 8; ++cc) s2 += pp_c[cc * 129 + tid];
            atomicAdd(&part[(size_t)(r & 7) * n + j0 + tid], s2);
        }
    }
}

// ---------------- kernel D1: per-row finalize, block partials ----------------
__global__ __launch_bounds__(256) void finalize1_kernel(
    const float* __restrict__ pos_sum, const float* __restrict__ part,
    float* __restrict__ bpart, int n)
{
    const int tid = threadIdx.x;
    const int i = blockIdx.x * 256 + tid;
    float s = 0.f;
    #pragma unroll
    for (int sl = 0; sl < 8; ++sl) s += part[(size_t)sl * n + i];
    const bool has = (s > 0.f);
    float l = has ? (0.5f * log1pf(pos_sum[i]) + 0.02f * log1pf(s)) : 0.f;
    float nno = has ? 0.f : 1.f;
    const int lane = tid & 63, wid = tid >> 6;
    __shared__ float rb[2][4];
    l = waveSum(l); nno = waveSum(nno);
    if (lane == 0) { rb[0][wid] = l; rb[1][wid] = nno; }
    __syncthreads();
    if (tid == 0) {
        bpart[blockIdx.x]      = rb[0][0] + rb[0][1] + rb[0][2] + rb[0][3];
        bpart[64 + blockIdx.x] = rb[1][0] + rb[1][1] + rb[1][2] + rb[1][3];
    }
}

// ---------------- kernel D2: final scalar outputs ----------------
__global__ __launch_bounds__(64) void finalize2_kernel(
    const float* __restrict__ bpart, const float* __restrict__ last4,
    float* __restrict__ out, int n, int nb1)
{
    const int tid = threadIdx.x;
    float l = (tid < nb1) ? bpart[tid] : 0.f;
    float p = (tid < nb1) ? bpart[64 + tid] : 0.f;
    l = waveSum(l); p = waveSum(p);
    if (tid == 0) {
        out[0] = l / (float)n;
        out[1] = p / (float)n;
        out[2] = last4[0] / fmaxf(last4[1], 1.f);
        out[3] = last4[2] / fmaxf(last4[3], 1.f);
    }
}

// ---------------- launch ----------------
extern "C" void kernel_launch(void* const* d_in, const int* in_sizes, int n_in,
                              void* d_out, int out_size, void* d_ws, size_t ws_size,
                              hipStream_t stream) {
    const float* x = (const float*)d_in[0];
    const int*   t = (const int*)d_in[1];
    const int n = in_sizes[1];   // 8192

    float* ws      = (float*)d_ws;
    float* pos_min = ws;                       // [n]
    float* pos_sum = ws + n;                   // [n]
    float* last4   = ws + 2 * n;               // [4]   zero-init
    float* part    = ws + 2 * n + 4;           // [8*n] zero-init
    float* bpart   = ws + 10 * n + 4;          // [128]
    int*   offs    = (int*)(ws + 10 * n + 132);           // [NL+1]
    int*   list    = (int*)(ws + 10 * n + 132 + NL + 1);  // [n]
    size_t xb_off  = ((size_t)(11 * n + 132 + NL + 1) + 3) & ~(size_t)3;
    ushort* xb     = (ushort*)(ws + xb_off);              // [n*128] bf16, 16B aligned

    hipMemsetAsync(last4, 0, (size_t)(8 * n + 4) * sizeof(float), stream);

    const int total8 = n * D / 8;
    const int nconv = (total8 + 255) / 256;
    prep_kernel<<<nconv + 1, 256, 0, stream>>>(x, xb, total8, t, offs, list, n, nconv);

    pos_kernel3<<<dim3(NL, 8), 256, 0, stream>>>(x, xb, offs, list,
                                                 pos_min, pos_sum, last4, n);

    const int nb = n / 128;                    // 64
    const int ntri = nb * (nb + 1) / 2;        // 2080
    neg_kernel_tri<<<ntri, 256, 0, stream>>>(xb, t, pos_min, part, last4, n);

    const int nb1 = n / 256;                   // 32
    finalize1_kernel<<<nb1, 256, 0, stream>>>(pos_sum, part, bpart, n);
    finalize2_kernel<<<1, 64, 0, stream>>>(bpart, last4, (float*)d_out, n, nb1);
}